// Round 3
// baseline (34004.987 us; speedup 1.0000x reference)
//
#include <hip/hip_runtime.h>

// LSTM_36807869726767 — round 3: persistent-kernel recurrence.
// One launch for all 512 timesteps: weights f32->f16 hi/lo split in-kernel,
// resident in LDS (82 KB/block); e-part GEMM folded into the step loop;
// c-state in registers; grid barrier via device-scope atomic counter.
// Grid = 256 blocks = 1/CU (co-residency guaranteed: LDS 82KB < 160KB).
// B=64, S=512, E=512, H=1024, NCLS=10, PAD=0. All float I/O is f32.

typedef _Float16 f16;
typedef __attribute__((ext_vector_type(8))) _Float16 f16x8;
typedef __attribute__((ext_vector_type(4))) _Float16 f16x4;
typedef __attribute__((ext_vector_type(4))) float f32x4;

#define Bn 64
#define Sn 512
#define En 512
#define Hn 1024

// padded LDS row strides (f16 units; 16B-aligned rows)
#define SE 520    // e-part rows: 512 data + 8 pad
#define SH 1032   // h-part rows: 1024 data + 8 pad

// ------------------------------------------------- gather e -> f16 [t][b][k]
__global__ __launch_bounds__(256) void gather_e_k(
    const int* __restrict__ x, const float* __restrict__ emb,
    f16* __restrict__ e16)
{
    size_t g = (size_t)blockIdx.x * 256 + threadIdx.x;   // 2,097,152 threads
    int row = (int)(g >> 6);          // t*64 + b
    int ko  = (int)(g & 63) * 8;
    int t = row >> 6, b = row & 63;
    int tok = x[b * Sn + t];
    float4 a  = *(const float4*)&emb[(size_t)tok * En + ko];
    float4 a2 = *(const float4*)&emb[(size_t)tok * En + ko + 4];
    float v[8] = {a.x, a.y, a.z, a.w, a2.x, a2.y, a2.z, a2.w};
    f16x8 h;
    #pragma unroll
    for (int i = 0; i < 8; ++i) h[i] = (f16)v[i];
    *(f16x8*)&e16[(size_t)row * En + ko] = h;
}

// ------------------------------------------------------------- Wa f32 -> f16
__global__ __launch_bounds__(256) void split_wa_k(
    const float* __restrict__ Wa, f16* __restrict__ hi)
{
    size_t g = ((size_t)blockIdx.x * 256 + threadIdx.x) * 8;
    float4 a = *(const float4*)&Wa[g];
    float4 b = *(const float4*)&Wa[g + 4];
    float v[8] = {a.x, a.y, a.z, a.w, b.x, b.y, b.z, b.w};
    f16x8 h;
    #pragma unroll
    for (int i = 0; i < 8; ++i) h[i] = (f16)v[i];
    *(f16x8*)&hi[g] = h;
}

// ------------------------------------------- persistent LSTM recurrence
// Block bk owns cells d0=4*bk..d0+3 (16 gate rows j=(n>>2)*1024+d0+(n&3)).
// Wave w handles batch rows w*16..w*16+15. K_eff = 512(e,1-term) + 1024*3(h).
__global__ __launch_bounds__(256) void lstm_persist_k(
    const f16* __restrict__ e16,     // [512][64][512]
    const float* __restrict__ Wg,    // [4096][1536] f32
    const float* __restrict__ bg,    // [4096]
    f16* __restrict__ h0h, f16* __restrict__ h0l,   // [64][1024] ping
    f16* __restrict__ h1h, f16* __restrict__ h1l,   // [64][1024] pong
    f16* __restrict__ hs_hi, f16* __restrict__ hs_lo, // [64][512][1024]
    unsigned* __restrict__ cnt)
{
    __shared__ f16 Wse[16 * SE];
    __shared__ f16 Wsh[16 * SH];
    __shared__ f16 Wsl[16 * SH];

    const int tid = threadIdx.x;
    const int bk  = blockIdx.x;     // 0..255
    const int d0  = bk * 4;

    // ---- one-time: stage + split this block's 16 weight rows (f32 -> hi/lo)
    {
        int n = tid >> 4, l16 = tid & 15;
        int j = (n >> 2) * 1024 + d0 + (n & 3);
        const float* src = Wg + (size_t)j * 1536;
        for (int k = l16 * 4; k < 1536; k += 64) {
            float4 v = *(const float4*)&src[k];
            float vv[4] = {v.x, v.y, v.z, v.w};
            f16x4 hi, lo;
            #pragma unroll
            for (int i = 0; i < 4; ++i) {
                f16 hv = (f16)vv[i];
                hi[i] = hv;
                lo[i] = (f16)(vv[i] - (float)hv);
            }
            if (k < 512) {
                *(f16x4*)&Wse[n * SE + k] = hi;
            } else {
                *(f16x4*)&Wsh[n * SH + (k - 512)] = hi;
                *(f16x4*)&Wsl[n * SH + (k - 512)] = lo;
            }
        }
    }
    __syncthreads();

    const int lane = tid & 63;
    const int w    = tid >> 6;        // wave index: m-tile (16 batch rows)
    const int cl   = lane & 15;
    const int q    = lane >> 4;
    const int b    = w * 16 + cl;     // A-row (batch) this lane loads
    const int ko   = q * 8;
    const int co   = cl & 3;
    const int jcol = (cl >> 2) * 1024 + d0 + (cl & 3);  // D-column -> gate row
    const float bgv = bg[jcol];

    const f16* Wse_r = &Wse[cl * SE + ko];
    const f16* Wsh_r = &Wsh[cl * SH + ko];
    const f16* Wsl_r = &Wsl[cl * SH + ko];

    float cst[4] = {0.f, 0.f, 0.f, 0.f};   // c-state: 4 cells x this lane's rows
    long bail = 0;

    for (int t = 0; t < Sn; ++t) {
        const f16* hih = (t & 1) ? h1h : h0h;
        const f16* hil = (t & 1) ? h1l : h0l;
        f16* hoh = (t & 1) ? h0h : h1h;
        f16* hol = (t & 1) ? h0l : h1l;

        const f16* Ae = e16 + ((size_t)t * 64 + b) * En + ko;
        const f16* Ah = hih + (size_t)b * Hn + ko;
        const f16* Al = hil + (size_t)b * Hn + ko;

        f32x4 acc = {0.f, 0.f, 0.f, 0.f};
        #pragma unroll 4
        for (int ks = 0; ks < 16; ++ks) {   // e-part, single term
            f16x8 a  = *(const f16x8*)&Ae[ks * 32];
            f16x8 bb = *(const f16x8*)&Wse_r[ks * 32];
            acc = __builtin_amdgcn_mfma_f32_16x16x32_f16(a, bb, acc, 0, 0, 0);
        }
        #pragma unroll 4
        for (int ks = 0; ks < 32; ++ks) {   // h-part, 3-term hi/lo
            f16x8 ah = *(const f16x8*)&Ah[ks * 32];
            f16x8 al = *(const f16x8*)&Al[ks * 32];
            f16x8 bh = *(const f16x8*)&Wsh_r[ks * 32];
            f16x8 bl = *(const f16x8*)&Wsl_r[ks * 32];
            acc = __builtin_amdgcn_mfma_f32_16x16x32_f16(ah, bh, acc, 0, 0, 0);
            acc = __builtin_amdgcn_mfma_f32_16x16x32_f16(ah, bl, acc, 0, 0, 0);
            acc = __builtin_amdgcn_mfma_f32_16x16x32_f16(al, bh, acc, 0, 0, 0);
        }

        // D layout: col=cl (gate row jcol), row=q*4+r (batch w*16+q*4+r)
        #pragma unroll
        for (int r = 0; r < 4; ++r) {
            float av = acc[r] + bgv;
            float iv = __shfl(av, (lane & 48) | co,      64);
            float fv = __shfl(av, (lane & 48) | 4 | co,  64);
            float gv = __shfl(av, (lane & 48) | 8 | co,  64);
            float ov = __shfl(av, (lane & 48) | 12 | co, 64);
            if (cl < 4) {
                int d  = d0 + co;
                int br = w * 16 + q * 4 + r;
                float i_ = 1.f / (1.f + expf(-iv));
                float f_ = 1.f / (1.f + expf(-fv));
                float g_ = tanhf(gv);
                float o_ = 1.f / (1.f + expf(-ov));
                float cn = f_ * cst[r] + i_ * g_;
                cst[r] = cn;
                float hn = o_ * tanhf(cn);
                f16 hh = (f16)hn;
                f16 hl = (f16)(hn - (float)hh);
                size_t hi_idx = (size_t)br * Hn + d;
                hoh[hi_idx] = hh; hol[hi_idx] = hl;
                size_t si = ((size_t)br * Sn + t) * Hn + d;
                hs_hi[si] = hh; hs_lo[si] = hl;
            }
        }

        // ---- grid barrier (monotonic count; release stores, acquire reads)
        __threadfence();
        __syncthreads();
        if (tid == 0) {
            __hip_atomic_fetch_add(cnt, 1u, __ATOMIC_ACQ_REL,
                                   __HIP_MEMORY_SCOPE_AGENT);
            unsigned tgt = 256u * (unsigned)(t + 1);
            long spins = 0;
            if (!bail) {
                while (__hip_atomic_load(cnt, __ATOMIC_ACQUIRE,
                                         __HIP_MEMORY_SCOPE_AGENT) < tgt) {
                    __builtin_amdgcn_s_sleep(4);
                    if (++spins > (1L << 22)) { bail = 1; break; }  // no-hang valve
                }
            }
        }
        __syncthreads();
        __threadfence();
    }
}

// ---------------------------------------------------------------- energy GEMM
__global__ __launch_bounds__(256) void energy_k(
    const f16* __restrict__ hs_hi,   // [B*S][H]
    const f16* __restrict__ Wa_hi,   // [H][H]
    const float* __restrict__ va,    // [H]
    float* __restrict__ energy)      // [B*S], pre-zeroed
{
    __shared__ f16 Was[128][136];
    const int bid = blockIdx.x;
    const int rb = bid >> 3;        // 512 row-blocks of 64
    const int nb = bid & 7;         // 8 col-blocks of 128
    const int tid = threadIdx.x;
    const int lane = tid & 63, w = tid >> 6, cl = lane & 15, q = lane >> 4;
    const int r0 = rb * 64 + w * 16 + cl;

    f32x4 acc[8];
    #pragma unroll
    for (int i = 0; i < 8; ++i) acc[i] = (f32x4){0.f, 0.f, 0.f, 0.f};

    for (int kc = 0; kc < 8; ++kc) {
        __syncthreads();
        for (int i = tid; i < 128 * 16; i += 256) {
            int dd = i >> 4;
            int kv = (i & 15) * 8;
            *(f16x8*)&Was[dd][kv] =
                *(const f16x8*)&Wa_hi[(size_t)(nb * 128 + dd) * Hn + kc * 128 + kv];
        }
        __syncthreads();
        const f16* A = hs_hi + (size_t)r0 * Hn + kc * 128;
        #pragma unroll
        for (int ks = 0; ks < 4; ++ks) {
            f16x8 a = *(const f16x8*)&A[ks * 32 + q * 8];
            #pragma unroll
            for (int nt = 0; nt < 8; ++nt) {
                f16x8 bb = *(const f16x8*)&Was[nt * 16 + cl][ks * 32 + q * 8];
                acc[nt] = __builtin_amdgcn_mfma_f32_16x16x32_f16(a, bb, acc[nt], 0, 0, 0);
            }
        }
    }

    float rowsum[4] = {0.f, 0.f, 0.f, 0.f};
    #pragma unroll
    for (int nt = 0; nt < 8; ++nt) {
        float vv = va[nb * 128 + nt * 16 + cl];
        #pragma unroll
        for (int r = 0; r < 4; ++r)
            rowsum[r] += tanhf(acc[nt][r]) * vv;
    }
    #pragma unroll
    for (int m = 1; m < 16; m <<= 1)
        #pragma unroll
        for (int r = 0; r < 4; ++r)
            rowsum[r] += __shfl_xor(rowsum[r], m, 64);
    if (cl == 0) {
        #pragma unroll
        for (int r = 0; r < 4; ++r)
            atomicAdd(&energy[(size_t)rb * 64 + w * 16 + q * 4 + r], rowsum[r]);
    }
}

// ------------------------------------------------- masked softmax + context
__global__ __launch_bounds__(256) void softctx_k(
    const float* __restrict__ energy, const int* __restrict__ x,
    const f16* __restrict__ hs_hi, const f16* __restrict__ hs_lo,
    float* __restrict__ context)   // [B][H]
{
    __shared__ float sm[512];
    __shared__ float red[256];
    const int b = blockIdx.x, tid = threadIdx.x;
    const int s0 = tid, s1 = tid + 256;
    float e0 = (x[b * Sn + s0] != 0) ? energy[b * Sn + s0] : -1e10f;
    float e1 = (x[b * Sn + s1] != 0) ? energy[b * Sn + s1] : -1e10f;
    red[tid] = fmaxf(e0, e1);
    __syncthreads();
    for (int st = 128; st > 0; st >>= 1) {
        if (tid < st) red[tid] = fmaxf(red[tid], red[tid + st]);
        __syncthreads();
    }
    float M = red[0];
    __syncthreads();
    float p0 = expf(e0 - M), p1 = expf(e1 - M);
    red[tid] = p0 + p1;
    __syncthreads();
    for (int st = 128; st > 0; st >>= 1) {
        if (tid < st) red[tid] += red[tid + st];
        __syncthreads();
    }
    float inv = 1.f / red[0];
    sm[s0] = p0 * inv; sm[s1] = p1 * inv;
    __syncthreads();

    const int d0v = tid * 4;
    float a0 = 0.f, a1 = 0.f, a2 = 0.f, a3 = 0.f;
    const f16* Hh = hs_hi + (size_t)b * Sn * Hn + d0v;
    const f16* Hl = hs_lo + (size_t)b * Sn * Hn + d0v;
    for (int s = 0; s < Sn; ++s) {
        float at = sm[s];
        f16x4 vh = *(const f16x4*)&Hh[(size_t)s * Hn];
        f16x4 vl = *(const f16x4*)&Hl[(size_t)s * Hn];
        a0 += at * ((float)vh[0] + (float)vl[0]);
        a1 += at * ((float)vh[1] + (float)vl[1]);
        a2 += at * ((float)vh[2] + (float)vl[2]);
        a3 += at * ((float)vh[3] + (float)vl[3]);
    }
    float* cp = context + (size_t)b * Hn + d0v;
    cp[0] = a0; cp[1] = a1; cp[2] = a2; cp[3] = a3;
}

// ---------------------------------------------------------------- logits
__global__ __launch_bounds__(256) void logits_k(
    const float* __restrict__ context, const float* __restrict__ WV,
    const float* __restrict__ bV, float* __restrict__ out)
{
    __shared__ float red[10][257];
    const int b = blockIdx.x, tid = threadIdx.x;
    const int d0v = tid * 4;
    float4 cv = *(const float4*)&context[(size_t)b * Hn + d0v];
    #pragma unroll
    for (int cls = 0; cls < 10; ++cls) {
        float4 wv = *(const float4*)&WV[cls * Hn + d0v];
        red[cls][tid] = cv.x * wv.x + cv.y * wv.y + cv.z * wv.z + cv.w * wv.w;
    }
    __syncthreads();
    for (int st = 128; st > 0; st >>= 1) {
        if (tid < st)
            #pragma unroll
            for (int cls = 0; cls < 10; ++cls)
                red[cls][tid] += red[cls][tid + st];
        __syncthreads();
    }
    if (tid < 10) out[b * 10 + tid] = red[tid][0] + bV[tid];
}

// ---------------------------------------------------------------- launch
extern "C" void kernel_launch(void* const* d_in, const int* in_sizes, int n_in,
                              void* d_out, int out_size, void* d_ws, size_t ws_size,
                              hipStream_t stream)
{
    const int*   x   = (const int*)d_in[0];
    const float* emb = (const float*)d_in[1];
    const float* Wg  = (const float*)d_in[2];
    const float* bg  = (const float*)d_in[3];
    const float* Wa  = (const float*)d_in[4];
    const float* va  = (const float*)d_in[5];
    const float* WV  = (const float*)d_in[6];
    const float* bV  = (const float*)d_in[7];
    float* out = (float*)d_out;

    char* ws = (char*)d_ws;
    size_t o = 0;
    auto alloc = [&](size_t bytes) { void* p = ws + o; o += (bytes + 255) & ~(size_t)255; return p; };
    f16*   e16   = (f16*)alloc((size_t)Sn * Bn * En * 2);      // 33.5 MB
    f16*   Wa_hi = (f16*)alloc((size_t)Hn * Hn * 2);           // 2 MB
    f16*   h0h   = (f16*)alloc((size_t)Bn * Hn * 2);
    f16*   h0l   = (f16*)alloc((size_t)Bn * Hn * 2);
    f16*   h1h   = (f16*)alloc((size_t)Bn * Hn * 2);
    f16*   h1l   = (f16*)alloc((size_t)Bn * Hn * 2);
    f16*   hs_hi = (f16*)alloc((size_t)Bn * Sn * Hn * 2);      // 67 MB
    f16*   hs_lo = (f16*)alloc((size_t)Bn * Sn * Hn * 2);      // 67 MB
    float* energy= (float*)alloc((size_t)Bn * Sn * 4);
    float* ctx   = (float*)alloc((size_t)Bn * Hn * 4);
    unsigned* cnt= (unsigned*)alloc(256);
    // total ~171 MB

    hipMemsetAsync(h0h, 0, (size_t)Bn * Hn * 2, stream);
    hipMemsetAsync(h0l, 0, (size_t)Bn * Hn * 2, stream);
    hipMemsetAsync(energy, 0, (size_t)Bn * Sn * 4, stream);
    hipMemsetAsync(cnt, 0, 256, stream);

    gather_e_k<<<8192, 256, 0, stream>>>(x, emb, e16);
    split_wa_k<<<512, 256, 0, stream>>>(Wa, Wa_hi);

    lstm_persist_k<<<256, 256, 0, stream>>>(e16, Wg, bg,
                                            h0h, h0l, h1h, h1l,
                                            hs_hi, hs_lo, cnt);

    energy_k<<<512 * 8, 256, 0, stream>>>(hs_hi, Wa_hi, va, energy);
    softctx_k<<<Bn, 256, 0, stream>>>(energy, x, hs_hi, hs_lo, ctx);
    logits_k<<<Bn, 256, 0, stream>>>(ctx, WV, bV, out);
}

// Round 4
// 6242.299 us; speedup vs baseline: 5.4475x; 5.4475x over previous
//
#include <hip/hip_runtime.h>

// LSTM_36807869726767 — round 4: persistent recurrence WITHOUT L2 invalidation.
// Round-3 failure: __threadfence() (agent acquire/release) emitted buffer_inv
// per step -> every step refetched 320 KB/block from L3 at ~700cyc with 4
// waves/CU -> 66us/step, MfmaUtil 1.1%. This round:
//  - h state in write-once per-step slots h_pk[t][b][k] (u32 = f16 hi|lo
//    packed): readers can never hold stale lines -> NORMAL cached loads, no
//    acquire fence, L2 dedups the 32-block/XCD broadcast.
//  - h writes: relaxed agent-scope atomic stores (sc0 sc1 -> coherence point,
//    L2 stays clean). __syncthreads' vmcnt(0) drains them before arrival.
//  - two-level relaxed barrier (16 groups of 16 + root), no fences, asm-only
//    compiler barriers + workgroup acquire fence (lgkmcnt only, no buffer_inv).
//  - e-part MFMAs computed BEFORE the spin (independent of h) to hide barrier;
//    4 independent MFMA chains to hide MFMA latency at 1 wave/SIMD.
// B=64, S=512, E=512, H=1024, NCLS=10, PAD=0. All float I/O f32.

typedef _Float16 f16;
typedef __attribute__((ext_vector_type(8))) _Float16 f16x8;
typedef __attribute__((ext_vector_type(4))) float f32x4;

#define Bn 64
#define Sn 512
#define En 512
#define Hn 1024

#define SE 520    // LDS row stride, e-part (512 + 8 pad)
#define SH 1032   // LDS row stride, h-part (1024 + 8 pad)

// low16 of a|b pairs -> one dword (hi parts); high16 -> lo parts
#define PERM_HI 0x05040100u
#define PERM_LO 0x07060302u

// ------------------------------------------------- gather e -> f16 [t][b][k]
__global__ __launch_bounds__(256) void gather_e_k(
    const int* __restrict__ x, const float* __restrict__ emb,
    f16* __restrict__ e16)
{
    size_t g = (size_t)blockIdx.x * 256 + threadIdx.x;
    int row = (int)(g >> 6);          // t*64 + b
    int ko  = (int)(g & 63) * 8;
    int t = row >> 6, b = row & 63;
    int tok = x[b * Sn + t];
    float4 a  = *(const float4*)&emb[(size_t)tok * En + ko];
    float4 a2 = *(const float4*)&emb[(size_t)tok * En + ko + 4];
    float v[8] = {a.x, a.y, a.z, a.w, a2.x, a2.y, a2.z, a2.w};
    f16x8 h;
    #pragma unroll
    for (int i = 0; i < 8; ++i) h[i] = (f16)v[i];
    *(f16x8*)&e16[(size_t)row * En + ko] = h;
}

// ------------------------------------------------------------- Wa f32 -> f16
__global__ __launch_bounds__(256) void split_wa_k(
    const float* __restrict__ Wa, f16* __restrict__ hi)
{
    size_t g = ((size_t)blockIdx.x * 256 + threadIdx.x) * 8;
    float4 a = *(const float4*)&Wa[g];
    float4 b = *(const float4*)&Wa[g + 4];
    float v[8] = {a.x, a.y, a.z, a.w, b.x, b.y, b.z, b.w};
    f16x8 h;
    #pragma unroll
    for (int i = 0; i < 8; ++i) h[i] = (f16)v[i];
    *(f16x8*)&hi[g] = h;
}

// ------------------------------------------- persistent LSTM recurrence
// Block bk owns cells d0=4*bk..d0+3 (16 gate rows). Wave w = m-tile (16 batch
// rows). h state: h_pk[slot][b][k] u32 (hi|lo<<16); slot t = state entering
// step t; slot 0 zeroed; step t writes slot t+1.
__global__ __launch_bounds__(256) void lstm_persist_k(
    const f16* __restrict__ e16,      // [512*64][512]
    const float* __restrict__ Wg,     // [4096][1536] f32
    const float* __restrict__ bg,     // [4096]
    unsigned* __restrict__ h_pk,      // [513][64][1024] u32
    unsigned* __restrict__ bar)       // [16*32] group counters + [512] root
{
    __shared__ f16 Wse[16 * SE];
    __shared__ f16 Wsh[16 * SH];
    __shared__ f16 Wsl[16 * SH];

    const int tid = threadIdx.x;
    const int bk  = blockIdx.x;     // 0..255
    const int d0  = bk * 4;

    // ---- one-time: stage + split 16 weight rows (f32 -> f16 hi/lo) into LDS
    {
        int n = tid >> 4, l16 = tid & 15;
        int j = (n >> 2) * 1024 + d0 + (n & 3);
        const float* src = Wg + (size_t)j * 1536;
        for (int k = l16 * 4; k < 1536; k += 64) {
            float4 v = *(const float4*)&src[k];
            float vv[4] = {v.x, v.y, v.z, v.w};
            #pragma unroll
            for (int i = 0; i < 4; ++i) {
                f16 hv = (f16)vv[i];
                f16 lv = (f16)(vv[i] - (float)hv);
                int kk = k + i;
                if (kk < 512) {
                    Wse[n * SE + kk] = hv;
                } else {
                    Wsh[n * SH + (kk - 512)] = hv;
                    Wsl[n * SH + (kk - 512)] = lv;
                }
            }
        }
    }
    __syncthreads();

    const int lane = tid & 63;
    const int w    = tid >> 6;
    const int cl   = lane & 15;
    const int q    = lane >> 4;
    const int b    = w * 16 + cl;
    const int ko   = q * 8;
    const int co   = cl & 3;
    const int jcol = (cl >> 2) * 1024 + d0 + (cl & 3);
    const float bgv = bg[jcol];

    const f16* Wse_r = &Wse[cl * SE + ko];
    const f16* Wsh_r = &Wsh[cl * SH + ko];
    const f16* Wsl_r = &Wsl[cl * SH + ko];

    unsigned* grp  = &bar[(bk >> 4) * 32];
    unsigned* root = &bar[512];

    float cst[4] = {0.f, 0.f, 0.f, 0.f};
    int bail = 0;

    for (int t = 0; t < Sn; ++t) {
        // ---- e-part (independent of h) — runs while barrier settles
        const f16* Ae = e16 + ((size_t)t * 64 + b) * En + ko;
        f32x4 accE = {0.f, 0.f, 0.f, 0.f};
        #pragma unroll 4
        for (int ks = 0; ks < 16; ++ks) {
            f16x8 a  = *(const f16x8*)&Ae[ks * 32];
            f16x8 bb = *(const f16x8*)&Wse_r[ks * 32];
            accE = __builtin_amdgcn_mfma_f32_16x16x32_f16(a, bb, accE, 0, 0, 0);
        }

        // ---- wait for step t-1 (root >= 16*t); relaxed spin, no acquire
        if (tid == 0 && t > 0 && !bail) {
            unsigned tgt = 16u * (unsigned)t;
            long spins = 0;
            while (__hip_atomic_load(root, __ATOMIC_RELAXED,
                                     __HIP_MEMORY_SCOPE_AGENT) < tgt) {
                __builtin_amdgcn_s_sleep(4);
                if (++spins > (1L << 24)) { bail = 1; break; }
            }
        }
        __syncthreads();
        __builtin_amdgcn_fence(__ATOMIC_ACQUIRE, "workgroup"); // no buffer_inv
        __asm__ __volatile__("" ::: "memory");

        // ---- h-part: normal cached loads of write-once slot t (L2 dedups)
        const unsigned* Ap = h_pk + ((size_t)t * 64 + b) * Hn + ko;
        f32x4 acc1 = {0.f, 0.f, 0.f, 0.f};
        f32x4 acc2 = {0.f, 0.f, 0.f, 0.f};
        f32x4 acc3 = {0.f, 0.f, 0.f, 0.f};
        #pragma unroll 4
        for (int ks = 0; ks < 32; ++ks) {
            uint4 p0 = *(const uint4*)&Ap[ks * 32];
            uint4 p1 = *(const uint4*)&Ap[ks * 32 + 4];
            union { unsigned u[4]; f16x8 v; } Ah, Al;
            Ah.u[0] = __builtin_amdgcn_perm(p0.y, p0.x, PERM_HI);
            Ah.u[1] = __builtin_amdgcn_perm(p0.w, p0.z, PERM_HI);
            Ah.u[2] = __builtin_amdgcn_perm(p1.y, p1.x, PERM_HI);
            Ah.u[3] = __builtin_amdgcn_perm(p1.w, p1.z, PERM_HI);
            Al.u[0] = __builtin_amdgcn_perm(p0.y, p0.x, PERM_LO);
            Al.u[1] = __builtin_amdgcn_perm(p0.w, p0.z, PERM_LO);
            Al.u[2] = __builtin_amdgcn_perm(p1.y, p1.x, PERM_LO);
            Al.u[3] = __builtin_amdgcn_perm(p1.w, p1.z, PERM_LO);
            f16x8 bh = *(const f16x8*)&Wsh_r[ks * 32];
            f16x8 bl = *(const f16x8*)&Wsl_r[ks * 32];
            acc1 = __builtin_amdgcn_mfma_f32_16x16x32_f16(Ah.v, bh, acc1, 0, 0, 0);
            acc2 = __builtin_amdgcn_mfma_f32_16x16x32_f16(Ah.v, bl, acc2, 0, 0, 0);
            acc3 = __builtin_amdgcn_mfma_f32_16x16x32_f16(Al.v, bh, acc3, 0, 0, 0);
        }
        f32x4 acc;
        #pragma unroll
        for (int r = 0; r < 4; ++r)
            acc[r] = (accE[r] + acc1[r]) + (acc2[r] + acc3[r]);

        // ---- cell update. D: col=cl (gate jcol), row=q*4+r (batch w*16+q*4+r)
        #pragma unroll
        for (int r = 0; r < 4; ++r) {
            float av = acc[r] + bgv;
            float iv = __shfl(av, (lane & 48) | co,      64);
            float fv = __shfl(av, (lane & 48) | 4 | co,  64);
            float gv = __shfl(av, (lane & 48) | 8 | co,  64);
            float ov = __shfl(av, (lane & 48) | 12 | co, 64);
            if (cl < 4) {
                int d  = d0 + co;
                int br = w * 16 + q * 4 + r;
                float i_ = 1.f / (1.f + expf(-iv));
                float f_ = 1.f / (1.f + expf(-fv));
                float g_ = tanhf(gv);
                float o_ = 1.f / (1.f + expf(-ov));
                float cn = f_ * cst[r] + i_ * g_;
                cst[r] = cn;
                float hn = o_ * tanhf(cn);
                f16 hh = (f16)hn;
                f16 hl = (f16)(hn - (float)hh);
                unsigned pkv = (unsigned)__builtin_bit_cast(unsigned short, hh)
                             | ((unsigned)__builtin_bit_cast(unsigned short, hl) << 16);
                // to coherence point (sc0 sc1), bypasses L2 -> L2 stays clean
                __hip_atomic_store(&h_pk[((size_t)(t + 1) * 64 + br) * Hn + d],
                                   pkv, __ATOMIC_RELAXED, __HIP_MEMORY_SCOPE_AGENT);
            }
        }

        // ---- arrive: __syncthreads drains vmcnt(0) per wave (stores acked)
        __syncthreads();
        __asm__ __volatile__("" ::: "memory");
        if (tid == 0) {
            unsigned prev = __hip_atomic_fetch_add(grp, 1u, __ATOMIC_RELAXED,
                                                   __HIP_MEMORY_SCOPE_AGENT);
            if ((prev & 15u) == 15u)   // 16th arrival of this step in group
                __hip_atomic_fetch_add(root, 1u, __ATOMIC_RELAXED,
                                       __HIP_MEMORY_SCOPE_AGENT);
        }
    }
}

// ---------------------------------------------------------------- energy GEMM
// rows r = t*64+b (h_pk linear row r+64); energy[r] += tanh(row.Wa[d]) * va[d]
__global__ __launch_bounds__(256) void energy_k(
    const unsigned* __restrict__ h_pk,  // [513*64][1024] u32
    const f16* __restrict__ Wa_hi,      // [H][H]
    const float* __restrict__ va,       // [H]
    float* __restrict__ energy)         // [B*S] (r-indexed), pre-zeroed
{
    __shared__ f16 Was[128][136];
    const int bid = blockIdx.x;
    const int rb = bid >> 3;
    const int nb = bid & 7;
    const int tid = threadIdx.x;
    const int lane = tid & 63, w = tid >> 6, cl = lane & 15, q = lane >> 4;
    const int r0 = rb * 64 + w * 16 + cl;

    f32x4 acc[8];
    #pragma unroll
    for (int i = 0; i < 8; ++i) acc[i] = (f32x4){0.f, 0.f, 0.f, 0.f};

    for (int kc = 0; kc < 8; ++kc) {
        __syncthreads();
        for (int i = tid; i < 128 * 16; i += 256) {
            int dd = i >> 4;
            int kv = (i & 15) * 8;
            *(f16x8*)&Was[dd][kv] =
                *(const f16x8*)&Wa_hi[(size_t)(nb * 128 + dd) * Hn + kc * 128 + kv];
        }
        __syncthreads();
        const unsigned* A = h_pk + (size_t)(r0 + 64) * Hn + kc * 128;
        #pragma unroll
        for (int ks = 0; ks < 4; ++ks) {
            uint4 p0 = *(const uint4*)&A[ks * 32 + q * 8];
            uint4 p1 = *(const uint4*)&A[ks * 32 + q * 8 + 4];
            union { unsigned u[4]; f16x8 v; } Ah;
            Ah.u[0] = __builtin_amdgcn_perm(p0.y, p0.x, PERM_HI);
            Ah.u[1] = __builtin_amdgcn_perm(p0.w, p0.z, PERM_HI);
            Ah.u[2] = __builtin_amdgcn_perm(p1.y, p1.x, PERM_HI);
            Ah.u[3] = __builtin_amdgcn_perm(p1.w, p1.z, PERM_HI);
            #pragma unroll
            for (int nt = 0; nt < 8; ++nt) {
                f16x8 bb = *(const f16x8*)&Was[nt * 16 + cl][ks * 32 + q * 8];
                acc[nt] = __builtin_amdgcn_mfma_f32_16x16x32_f16(Ah.v, bb, acc[nt], 0, 0, 0);
            }
        }
    }

    float rowsum[4] = {0.f, 0.f, 0.f, 0.f};
    #pragma unroll
    for (int nt = 0; nt < 8; ++nt) {
        float vv = va[nb * 128 + nt * 16 + cl];
        #pragma unroll
        for (int r = 0; r < 4; ++r)
            rowsum[r] += tanhf(acc[nt][r]) * vv;
    }
    #pragma unroll
    for (int m = 1; m < 16; m <<= 1)
        #pragma unroll
        for (int r = 0; r < 4; ++r)
            rowsum[r] += __shfl_xor(rowsum[r], m, 64);
    if (cl == 0) {
        #pragma unroll
        for (int r = 0; r < 4; ++r)
            atomicAdd(&energy[(size_t)rb * 64 + w * 16 + q * 4 + r], rowsum[r]);
    }
}

// ------------------------------------------------- masked softmax + context
// energy index for (b,s) = s*64 + b
__global__ __launch_bounds__(256) void softctx_k(
    const float* __restrict__ energy, const int* __restrict__ x,
    const unsigned* __restrict__ h_pk,
    float* __restrict__ context)   // [B][H]
{
    __shared__ float sm[512];
    __shared__ float red[256];
    const int b = blockIdx.x, tid = threadIdx.x;
    const int s0 = tid, s1 = tid + 256;
    float e0 = (x[b * Sn + s0] != 0) ? energy[s0 * 64 + b] : -1e10f;
    float e1 = (x[b * Sn + s1] != 0) ? energy[s1 * 64 + b] : -1e10f;
    red[tid] = fmaxf(e0, e1);
    __syncthreads();
    for (int st = 128; st > 0; st >>= 1) {
        if (tid < st) red[tid] = fmaxf(red[tid], red[tid + st]);
        __syncthreads();
    }
    float M = red[0];
    __syncthreads();
    float p0 = expf(e0 - M), p1 = expf(e1 - M);
    red[tid] = p0 + p1;
    __syncthreads();
    for (int st = 128; st > 0; st >>= 1) {
        if (tid < st) red[tid] += red[tid + st];
        __syncthreads();
    }
    float inv = 1.f / red[0];
    sm[s0] = p0 * inv; sm[s1] = p1 * inv;
    __syncthreads();

    const int d0v = tid * 4;
    float a0 = 0.f, a1 = 0.f, a2 = 0.f, a3 = 0.f;
    for (int s = 0; s < Sn; ++s) {
        float at = sm[s];
        uint4 pv = *(const uint4*)&h_pk[((size_t)(s + 1) * 64 + b) * Hn + d0v];
        union { unsigned u; _Float16 h[2]; } c0, c1, c2, c3;
        c0.u = pv.x; c1.u = pv.y; c2.u = pv.z; c3.u = pv.w;
        a0 += at * ((float)c0.h[0] + (float)c0.h[1]);
        a1 += at * ((float)c1.h[0] + (float)c1.h[1]);
        a2 += at * ((float)c2.h[0] + (float)c2.h[1]);
        a3 += at * ((float)c3.h[0] + (float)c3.h[1]);
    }
    float* cp = context + (size_t)b * Hn + d0v;
    cp[0] = a0; cp[1] = a1; cp[2] = a2; cp[3] = a3;
}

// ---------------------------------------------------------------- logits
__global__ __launch_bounds__(256) void logits_k(
    const float* __restrict__ context, const float* __restrict__ WV,
    const float* __restrict__ bV, float* __restrict__ out)
{
    __shared__ float red[10][257];
    const int b = blockIdx.x, tid = threadIdx.x;
    const int d0v = tid * 4;
    float4 cv = *(const float4*)&context[(size_t)b * Hn + d0v];
    #pragma unroll
    for (int cls = 0; cls < 10; ++cls) {
        float4 wv = *(const float4*)&WV[cls * Hn + d0v];
        red[cls][tid] = cv.x * wv.x + cv.y * wv.y + cv.z * wv.z + cv.w * wv.w;
    }
    __syncthreads();
    for (int st = 128; st > 0; st >>= 1) {
        if (tid < st)
            #pragma unroll
            for (int cls = 0; cls < 10; ++cls)
                red[cls][tid] += red[cls][tid + st];
        __syncthreads();
    }
    if (tid < 10) out[b * 10 + tid] = red[tid][0] + bV[tid];
}

// ---------------------------------------------------------------- launch
extern "C" void kernel_launch(void* const* d_in, const int* in_sizes, int n_in,
                              void* d_out, int out_size, void* d_ws, size_t ws_size,
                              hipStream_t stream)
{
    const int*   x   = (const int*)d_in[0];
    const float* emb = (const float*)d_in[1];
    const float* Wg  = (const float*)d_in[2];
    const float* bg  = (const float*)d_in[3];
    const float* Wa  = (const float*)d_in[4];
    const float* va  = (const float*)d_in[5];
    const float* WV  = (const float*)d_in[6];
    const float* bV  = (const float*)d_in[7];
    float* out = (float*)d_out;

    char* ws = (char*)d_ws;
    size_t o = 0;
    auto alloc = [&](size_t bytes) { void* p = ws + o; o += (bytes + 255) & ~(size_t)255; return p; };
    f16*      e16   = (f16*)alloc((size_t)Sn * Bn * En * 2);        // 33.5 MB
    f16*      Wa_hi = (f16*)alloc((size_t)Hn * Hn * 2);             // 2 MB
    unsigned* h_pk  = (unsigned*)alloc((size_t)(Sn + 1) * Bn * Hn * 4); // 134.5 MB
    float*    energy= (float*)alloc((size_t)Bn * Sn * 4);
    float*    ctx   = (float*)alloc((size_t)Bn * Hn * 4);
    unsigned* bar   = (unsigned*)alloc(4096);
    // total ~170 MB

    hipMemsetAsync(h_pk, 0, (size_t)Bn * Hn * 4, stream);   // slot 0 = zeros
    hipMemsetAsync(energy, 0, (size_t)Bn * Sn * 4, stream);
    hipMemsetAsync(bar, 0, 4096, stream);

    gather_e_k<<<8192, 256, 0, stream>>>(x, emb, e16);
    split_wa_k<<<512, 256, 0, stream>>>(Wa, Wa_hi);

    lstm_persist_k<<<256, 256, 0, stream>>>(e16, Wg, bg, h_pk, bar);

    energy_k<<<512 * 8, 256, 0, stream>>>(h_pk, Wa_hi, va, energy);
    softctx_k<<<Bn, 256, 0, stream>>>(energy, x, h_pk, ctx);
    logits_k<<<Bn, 256, 0, stream>>>(ctx, WV, bV, out);
}